// Round 1
// baseline (35404.211 us; speedup 1.0000x reference)
//
#include <hip/hip_runtime.h>
#include <hip/hip_fp16.h>
#include <cstdint>
#include <cstddef>

typedef _Float16 f16x8 __attribute__((ext_vector_type(8)));
typedef float    f32x4 __attribute__((ext_vector_type(4)));

#define MFMA(A,B,C) __builtin_amdgcn_mfma_f32_16x16x32_f16((A),(B),(C),0,0,0)

// ---- problem constants ----
#define NRES  2048
#define DIN   32
#define DOUT  16
#define HDIM  128
#define BBATCH 64
#define TSTEPS 256
#define WCOLS 4224     // 2048 (W_res) + 2048 (W_att) + 128 (W_h1)
#define NBLK  512      // persistent grid; 2 blocks/CU on 256 CUs

// ---- workspace layout (bytes, all 256-aligned) ----
#define OFF_WBIG  ((size_t)0)          // 4224*2048 f16   = 17,301,504
#define OFF_BIAS  ((size_t)17301504)   // 4224 f32        =     16,896
#define OFF_WE2H  ((size_t)17318400)   // 128*128 f16     =     32,768
#define OFF_WE3H  ((size_t)17351168)   // 2048*128 f16    =    524,288
#define OFF_S16   ((size_t)17875456)   // 64*2048 f16     =    262,144
#define OFF_YP    ((size_t)18137600)   // 2*64*4224 f32   =  2,162,688
#define OFF_CNT   ((size_t)20300288)   // 64 B counter
// total ~20.3 MB

__device__ __forceinline__ float gelu_exact(float v) {
  return 0.5f * v * (1.0f + erff(v * 0.70710678118654752f));
}

// ---------------- prep kernels ----------------

__global__ void k_cast(const float* __restrict__ src, _Float16* __restrict__ dst, int n) {
  int i = blockIdx.x * blockDim.x + threadIdx.x;
  int stride = gridDim.x * blockDim.x;
  for (; i < n; i += stride) dst[i] = (_Float16)src[i];
}

// b_att[c] = dot(Wproj[c,:], bv) + bproj[c]  -> bias_big[2048+c]
__global__ void k_batt(const float* __restrict__ Wproj, const float* __restrict__ bv,
                       const float* __restrict__ bproj, float* __restrict__ bias_big) {
  int c = blockIdx.x, tid = threadIdx.x;
  float p = 0.f;
  for (int k = tid; k < NRES; k += 256) p += Wproj[(size_t)c * NRES + k] * bv[k];
  for (int m = 1; m < 64; m <<= 1) p += __shfl_xor(p, m);
  __shared__ float r4[4];
  if ((tid & 63) == 0) r4[tid >> 6] = p;
  __syncthreads();
  if (tid == 0) bias_big[2048 + c] = r4[0] + r4[1] + r4[2] + r4[3] + bproj[c];
}

// b_h1[h] = dot(We1[h,:], b_att) + be1[h] -> bias_big[4096+h]
__global__ void k_bh1(const float* __restrict__ We1, const float* __restrict__ be1,
                      float* __restrict__ bias_big) {
  int h = blockIdx.x, tid = threadIdx.x;
  float p = 0.f;
  for (int n = tid; n < NRES; n += 256) p += We1[(size_t)h * NRES + n] * bias_big[2048 + n];
  for (int m = 1; m < 64; m <<= 1) p += __shfl_xor(p, m);
  __shared__ float r4[4];
  if ((tid & 63) == 0) r4[tid >> 6] = p;
  __syncthreads();
  if (tid == 0) bias_big[4096 + h] = r4[0] + r4[1] + r4[2] + r4[3] + be1[h];
}

// W_att = Wproj @ Wv  (2048x2048x2048), f16 MFMA, fp32 accum.
// out row-major over k -> written as Wbig rows 2048..4095  ( Wbig[2048+c][k] )
__global__ void __launch_bounds__(256) k_gemm1(const float* __restrict__ Wproj,
                                               const float* __restrict__ Wv,
                                               _Float16* __restrict__ wbig) {
  __shared__ _Float16 BT[64][40];   // [k within 64-block][m within 32-chunk], padded
  const int kblock = blockIdx.x, cblock = blockIdx.y;
  const int tid = threadIdx.x, wv = tid >> 6, lane = tid & 63;
  const int l4 = lane >> 4, l15 = lane & 15;
  const int crow0 = cblock * 64 + wv * 16;
  f32x4 acc[4];
  f32x4 zero = {0.f, 0.f, 0.f, 0.f};
  for (int i = 0; i < 4; ++i) acc[i] = zero;

  for (int mc = 0; mc < 64; ++mc) {
    const int m0 = mc * 32;
    {
      int m = tid >> 3, kk = (tid & 7) * 8;
      const float* src = &Wv[(size_t)(m0 + m) * NRES + kblock * 64 + kk];
      float4 v0 = *(const float4*)src;
      float4 v1 = *(const float4*)(src + 4);
      float tmp[8] = {v0.x, v0.y, v0.z, v0.w, v1.x, v1.y, v1.z, v1.w};
      #pragma unroll
      for (int j = 0; j < 8; ++j) BT[kk + j][m] = (_Float16)tmp[j];
    }
    __syncthreads();
    const float* pa = &Wproj[(size_t)(crow0 + l15) * NRES + m0 + l4 * 8];
    float4 a0 = *(const float4*)pa;
    float4 a1 = *(const float4*)(pa + 4);
    f16x8 af;
    af[0]=(_Float16)a0.x; af[1]=(_Float16)a0.y; af[2]=(_Float16)a0.z; af[3]=(_Float16)a0.w;
    af[4]=(_Float16)a1.x; af[5]=(_Float16)a1.y; af[6]=(_Float16)a1.z; af[7]=(_Float16)a1.w;
    #pragma unroll
    for (int kt = 0; kt < 4; ++kt) {
      f16x8 bf = *(const f16x8*)&BT[kt * 16 + l15][l4 * 8];
      acc[kt] = MFMA(af, bf, acc[kt]);
    }
    __syncthreads();
  }
  #pragma unroll
  for (int kt = 0; kt < 4; ++kt)
    #pragma unroll
    for (int i = 0; i < 4; ++i) {
      int c = crow0 + l4 * 4 + i;
      int k = kblock * 64 + kt * 16 + l15;
      wbig[(size_t)(2048 + c) * NRES + k] = (_Float16)acc[kt][i];
    }
}

// W_h1 = We1 @ W_att  (128x2048, K=2048) -> Wbig rows 4096..4223
__global__ void __launch_bounds__(256) k_gemm2(const float* __restrict__ We1,
                                               _Float16* __restrict__ wbig) {
  __shared__ _Float16 BT[64][40];
  const int kblock = blockIdx.x, hblock = blockIdx.y;
  const int tid = threadIdx.x, wv = tid >> 6, lane = tid & 63;
  const int l4 = lane >> 4, l15 = lane & 15;
  const int hrow0 = hblock * 64 + wv * 16;
  f32x4 acc[4];
  f32x4 zero = {0.f, 0.f, 0.f, 0.f};
  for (int i = 0; i < 4; ++i) acc[i] = zero;

  for (int nc = 0; nc < 64; ++nc) {
    const int n0 = nc * 32;
    {
      int n = tid >> 3, kk = (tid & 7) * 8;
      f16x8 v = *(const f16x8*)&wbig[(size_t)(2048 + n0 + n) * NRES + kblock * 64 + kk];
      #pragma unroll
      for (int j = 0; j < 8; ++j) BT[kk + j][n] = v[j];
    }
    __syncthreads();
    const float* pa = &We1[(size_t)(hrow0 + l15) * NRES + n0 + l4 * 8];
    float4 a0 = *(const float4*)pa;
    float4 a1 = *(const float4*)(pa + 4);
    f16x8 af;
    af[0]=(_Float16)a0.x; af[1]=(_Float16)a0.y; af[2]=(_Float16)a0.z; af[3]=(_Float16)a0.w;
    af[4]=(_Float16)a1.x; af[5]=(_Float16)a1.y; af[6]=(_Float16)a1.z; af[7]=(_Float16)a1.w;
    #pragma unroll
    for (int kt = 0; kt < 4; ++kt) {
      f16x8 bf = *(const f16x8*)&BT[kt * 16 + l15][l4 * 8];
      acc[kt] = MFMA(af, bf, acc[kt]);
    }
    __syncthreads();
  }
  #pragma unroll
  for (int kt = 0; kt < 4; ++kt)
    #pragma unroll
    for (int i = 0; i < 4; ++i) {
      int h = hrow0 + l4 * 4 + i;
      int k = kblock * 64 + kt * 16 + l15;
      wbig[(size_t)(4096 + h) * NRES + k] = (_Float16)acc[kt][i];
    }
}

// ---------------- main persistent kernel ----------------

__device__ __forceinline__ void gbar(unsigned* cnt, unsigned target) {
  __syncthreads();
  if (threadIdx.x == 0) {
    __threadfence();
    __hip_atomic_fetch_add(cnt, 1u, __ATOMIC_RELEASE, __HIP_MEMORY_SCOPE_AGENT);
    int spins = 0;
    while (__hip_atomic_load(cnt, __ATOMIC_RELAXED, __HIP_MEMORY_SCOPE_AGENT) < target) {
      __builtin_amdgcn_s_sleep(1);
      if (++spins > (1 << 22)) break;   // safety bail: broken barrier -> wrong answer, not hang
    }
    (void)__hip_atomic_load(cnt, __ATOMIC_ACQUIRE, __HIP_MEMORY_SCOPE_AGENT); // L1 inv
  }
  __syncthreads();
}

__global__ void __launch_bounds__(256, 2) k_main(
    const float* __restrict__ x, const float* __restrict__ W_in,
    const float* __restrict__ ln_g, const float* __restrict__ ln_b,
    const float* __restrict__ be2v, const float* __restrict__ be3v,
    const float* __restrict__ w_mu, const float* __restrict__ w_rho,
    const float* __restrict__ b_mu, const float* __restrict__ b_rho,
    const float* __restrict__ w_eps, const float* __restrict__ b_eps,
    const _Float16* __restrict__ wbig, const float* __restrict__ bias_big,
    const _Float16* __restrict__ we2h, const _Float16* __restrict__ we3h,
    _Float16* __restrict__ s16, float* __restrict__ yp,
    unsigned* __restrict__ cnt, float* __restrict__ out)
{
  const int b = blockIdx.x, tid = threadIdx.x;
  const int wv = tid >> 6, lane = tid & 63;
  const int l4 = lane >> 4, l15 = lane & 15;

  __shared__ float    lds_red[4][64][17];     // padded: conflict-light K-split reduce
  __shared__ _Float16 lds_h1[16][136];        // gelu(LN(h1)) f16, padded rows
  __shared__ _Float16 lds_g2[16][136];        // gelu(h2) f16
  __shared__ float    lds_x[16][36];          // x_t rows for this block

  // ---- S1 identity: strip of 16 output cols x K-half, 4 waves K-split ----
  const int strip = b >> 1, half = b & 1;
  const int koff = half * 1024 + wv * 256;
  const bool xd = ((b & 31) == 0);            // 16 blocks carry the 8 h1 strips x 2 halves
  const int strip2 = 256 + (b >> 6);
  const int koff2 = ((b >> 5) & 1) * 1024 + wv * 256;

  f16x8 Bf[8];
  #pragma unroll
  for (int ks = 0; ks < 8; ++ks)
    Bf[ks] = *(const f16x8*)&wbig[(size_t)(strip * 16 + l15) * NRES + koff + ks * 32 + l4 * 8];

  // ---- S3 identity: 16 rows x 16 cols of new state ----
  const int rg = b >> 7, cc = b & 127;
  const int rowbase = rg * 16, colbase = cc * 16;
  const int lr = wv * 4 + l4;                 // block-local row handled in LN phase

  float g8[8], bb8[8], bh8[8];
  #pragma unroll
  for (int jj = 0; jj < 8; ++jj) {
    g8[jj]  = ln_g[l15 + 16 * jj];
    bb8[jj] = ln_b[l15 + 16 * jj];
    bh8[jj] = bias_big[4096 + l15 + 16 * jj];
  }
  f16x8 We2f[2][4];
  float be2r[2];
  #pragma unroll
  for (int ct = 0; ct < 2; ++ct) {
    be2r[ct] = be2v[wv * 32 + ct * 16 + l15];
    #pragma unroll
    for (int ks = 0; ks < 4; ++ks)
      We2f[ct][ks] = *(const f16x8*)&we2h[(size_t)(wv * 32 + ct * 16 + l15) * HDIM + ks * 32 + l4 * 8];
  }
  f16x8 We3f[4];
  #pragma unroll
  for (int ks = 0; ks < 4; ++ks)
    We3f[ks] = *(const f16x8*)&we3h[(size_t)(colbase + l15) * HDIM + ks * 32 + l4 * 8];
  const float be3r  = be3v[colbase + l15];
  const float battr = bias_big[2048 + colbase + l15];

  const f32x4 zero = {0.f, 0.f, 0.f, 0.f};
  unsigned phase = 0;

  for (int t = 0; t < TSTEPS; ++t) {
    // ================= S1: Y = s @ [W_res|W_att|W_h1]^T (K-split partials) ==========
    f32x4 a0 = zero, a1 = zero, a2 = zero, a3 = zero;
    #pragma unroll
    for (int ks = 0; ks < 8; ++ks) {
      const int kk = koff + ks * 32 + l4 * 8;
      f16x8 A0 = *(const f16x8*)&s16[(size_t)(l15) * NRES + kk];
      f16x8 A1 = *(const f16x8*)&s16[(size_t)(16 + l15) * NRES + kk];
      f16x8 A2 = *(const f16x8*)&s16[(size_t)(32 + l15) * NRES + kk];
      f16x8 A3 = *(const f16x8*)&s16[(size_t)(48 + l15) * NRES + kk];
      a0 = MFMA(A0, Bf[ks], a0);
      a1 = MFMA(A1, Bf[ks], a1);
      a2 = MFMA(A2, Bf[ks], a2);
      a3 = MFMA(A3, Bf[ks], a3);
    }
    #pragma unroll
    for (int i = 0; i < 4; ++i) {
      lds_red[wv][lane][0 + i]  = a0[i];
      lds_red[wv][lane][4 + i]  = a1[i];
      lds_red[wv][lane][8 + i]  = a2[i];
      lds_red[wv][lane][12 + i] = a3[i];
    }
    __syncthreads();
    if (wv == 0) {
      #pragma unroll
      for (int q = 0; q < 4; ++q)
        #pragma unroll
        for (int i = 0; i < 4; ++i) {
          float s = lds_red[0][lane][q * 4 + i] + lds_red[1][lane][q * 4 + i]
                  + lds_red[2][lane][q * 4 + i] + lds_red[3][lane][q * 4 + i];
          int row = q * 16 + l4 * 4 + i;
          yp[(size_t)(half * 64 + row) * WCOLS + strip * 16 + l15] = s;
        }
    }
    if (xd) {   // extra duty: one of the 8 h1 strips (cols 4096..4223)
      f32x4 e0 = zero, e1 = zero, e2 = zero, e3 = zero;
      #pragma unroll
      for (int ks = 0; ks < 8; ++ks) {
        const int kk = koff2 + ks * 32 + l4 * 8;
        f16x8 Bx = *(const f16x8*)&wbig[(size_t)(strip2 * 16 + l15) * NRES + kk];
        f16x8 A0 = *(const f16x8*)&s16[(size_t)(l15) * NRES + kk];
        f16x8 A1 = *(const f16x8*)&s16[(size_t)(16 + l15) * NRES + kk];
        f16x8 A2 = *(const f16x8*)&s16[(size_t)(32 + l15) * NRES + kk];
        f16x8 A3 = *(const f16x8*)&s16[(size_t)(48 + l15) * NRES + kk];
        e0 = MFMA(A0, Bx, e0);
        e1 = MFMA(A1, Bx, e1);
        e2 = MFMA(A2, Bx, e2);
        e3 = MFMA(A3, Bx, e3);
      }
      __syncthreads();   // wave0 done reading lds_red
      #pragma unroll
      for (int i = 0; i < 4; ++i) {
        lds_red[wv][lane][0 + i]  = e0[i];
        lds_red[wv][lane][4 + i]  = e1[i];
        lds_red[wv][lane][8 + i]  = e2[i];
        lds_red[wv][lane][12 + i] = e3[i];
      }
      __syncthreads();
      if (wv == 0) {
        int h2f = (b >> 5) & 1;
        #pragma unroll
        for (int q = 0; q < 4; ++q)
          #pragma unroll
          for (int i = 0; i < 4; ++i) {
            float s = lds_red[0][lane][q * 4 + i] + lds_red[1][lane][q * 4 + i]
                    + lds_red[2][lane][q * 4 + i] + lds_red[3][lane][q * 4 + i];
            int row = q * 16 + l4 * 4 + i;
            yp[(size_t)(h2f * 64 + row) * WCOLS + strip2 * 16 + l15] = s;
          }
      }
    }
    ++phase;
    gbar(cnt, phase * NBLK);

    // ================= S3: LN -> GELU -> We2 -> GELU -> We3 -> state update =========
    if (tid < 128) {  // stage x_t rows for this block
      int xr = tid >> 3, k0 = (tid & 7) * 4;
      const float4 v = *(const float4*)&x[((size_t)(rowbase + xr) * TSTEPS + t) * DIN + k0];
      lds_x[xr][k0 + 0] = v.x; lds_x[xr][k0 + 1] = v.y;
      lds_x[xr][k0 + 2] = v.z; lds_x[xr][k0 + 3] = v.w;
    }
    // h1 (sum halves + bias), LayerNorm over 128, exact GELU
    float h1v[8];
    float s1 = 0.f, s2 = 0.f;
    const size_t yb0 = (size_t)(rowbase + lr) * WCOLS + 4096;
    const size_t yb1 = (size_t)(64 + rowbase + lr) * WCOLS + 4096;
    #pragma unroll
    for (int jj = 0; jj < 8; ++jj) {
      int j = l15 + 16 * jj;
      float v = yp[yb0 + j] + yp[yb1 + j] + bh8[jj];
      h1v[jj] = v; s1 += v; s2 += v * v;
    }
    #pragma unroll
    for (int m = 1; m < 16; m <<= 1) { s1 += __shfl_xor(s1, m); s2 += __shfl_xor(s2, m); }
    const float mu = s1 * (1.f / 128.f);
    const float var = s2 * (1.f / 128.f) - mu * mu;
    const float rs = rsqrtf(var + 1e-5f);
    #pragma unroll
    for (int jj = 0; jj < 8; ++jj) {
      int j = l15 + 16 * jj;
      float hn = (h1v[jj] - mu) * rs * g8[jj] + bb8[jj];
      lds_h1[lr][j] = (_Float16)gelu_exact(hn);
    }
    __syncthreads();
    // h2 = gelu(h @ We2^T + be2): each wave does 32 of the 128 cols
    f32x4 c0 = zero, c1 = zero;
    #pragma unroll
    for (int ks = 0; ks < 4; ++ks) {
      f16x8 af = *(const f16x8*)&lds_h1[l15][ks * 32 + l4 * 8];
      c0 = MFMA(af, We2f[0][ks], c0);
      c1 = MFMA(af, We2f[1][ks], c1);
    }
    #pragma unroll
    for (int i = 0; i < 4; ++i) {
      int rr = l4 * 4 + i;
      lds_g2[rr][wv * 32 + l15]      = (_Float16)gelu_exact(c0[i] + be2r[0]);
      lds_g2[rr][wv * 32 + 16 + l15] = (_Float16)gelu_exact(c1[i] + be2r[1]);
    }
    __syncthreads();
    // phys + state update (wave 0 owns this block's 16x16 output tile)
    if (wv == 0) {
      f32x4 accp = zero;
      #pragma unroll
      for (int ks = 0; ks < 4; ++ks) {
        f16x8 af = *(const f16x8*)&lds_g2[l15][ks * 32 + l4 * 8];
        accp = MFMA(af, We3f[ks], accp);
      }
      #pragma unroll
      for (int i = 0; i < 4; ++i) {
        int r2 = l4 * 4 + i, grow = rowbase + r2, col = colbase + l15;
        size_t ya = (size_t)grow * WCOLS;
        size_t yb = (size_t)(64 + grow) * WCOLS;
        float satt = yp[ya + 2048 + col] + yp[yb + 2048 + col] + battr;
        float rrv  = yp[ya + col] + yp[yb + col];
        float inp = 0.f;
        #pragma unroll
        for (int k = 0; k < DIN; ++k) inp += lds_x[r2][k] * W_in[col * DIN + k];
        float pv = accp[i] + be3r;
        float ns = 0.7f * satt + 0.3f * tanhf(inp + rrv + pv);
        s16[(size_t)grow * NRES + col] = (_Float16)ns;
      }
    }
    ++phase;
    gbar(cnt, phase * NBLK);
  }

  // ---- Bayesian output head: predictions[b][o] ----
  if (b < BBATCH) {
    float* red = &lds_red[0][0][0];   // reuse LDS: need 16*17 floats
    int o = tid >> 4, sg = tid & 15;
    float p = 0.f;
    for (int n = sg * 128; n < sg * 128 + 128; ++n) {
      float sv = (float)s16[(size_t)b * NRES + n];
      float w = w_mu[(size_t)o * NRES + n]
              + log1pf(expf(w_rho[(size_t)o * NRES + n])) * w_eps[(size_t)o * NRES + n];
      p += sv * w;
    }
    red[o * 17 + sg] = p;
    __syncthreads();
    if (tid < DOUT) {
      float sum = 0.f;
      for (int q = 0; q < 16; ++q) sum += red[tid * 17 + q];
      float bs = b_mu[tid] + log1pf(expf(b_rho[tid])) * b_eps[tid];
      out[b * DOUT + tid] = sum + bs;
    }
  }
}

// ---------------- host ----------------

extern "C" void kernel_launch(void* const* d_in, const int* in_sizes, int n_in,
                              void* d_out, int out_size, void* d_ws, size_t ws_size,
                              hipStream_t stream) {
  (void)in_sizes; (void)n_in; (void)out_size; (void)ws_size;
  const float* x     = (const float*)d_in[0];
  const float* W_in  = (const float*)d_in[1];
  const float* W_res = (const float*)d_in[2];
  const float* Wv    = (const float*)d_in[3];
  const float* bv    = (const float*)d_in[4];
  const float* Wproj = (const float*)d_in[5];
  const float* bproj = (const float*)d_in[6];
  const float* We1   = (const float*)d_in[7];
  const float* be1   = (const float*)d_in[8];
  const float* ln_g  = (const float*)d_in[9];
  const float* ln_b  = (const float*)d_in[10];
  const float* We2   = (const float*)d_in[11];
  const float* be2   = (const float*)d_in[12];
  const float* We3   = (const float*)d_in[13];
  const float* be3   = (const float*)d_in[14];
  const float* w_mu  = (const float*)d_in[15];
  const float* w_rho = (const float*)d_in[16];
  const float* b_mu  = (const float*)d_in[17];
  const float* b_rho = (const float*)d_in[18];
  const float* w_eps = (const float*)d_in[19];
  const float* b_eps = (const float*)d_in[20];
  float* out = (float*)d_out;

  char* ws = (char*)d_ws;
  _Float16* wbig     = (_Float16*)(ws + OFF_WBIG);
  float*    bias_big = (float*)(ws + OFF_BIAS);
  _Float16* we2h     = (_Float16*)(ws + OFF_WE2H);
  _Float16* we3h     = (_Float16*)(ws + OFF_WE3H);
  _Float16* s16      = (_Float16*)(ws + OFF_S16);
  float*    yp       = (float*)(ws + OFF_YP);
  unsigned* cnt      = (unsigned*)(ws + OFF_CNT);

  hipMemsetAsync(bias_big, 0, WCOLS * sizeof(float), stream);
  hipMemsetAsync(s16, 0, (size_t)BBATCH * NRES * sizeof(_Float16), stream);
  hipMemsetAsync(cnt, 0, 64, stream);

  k_cast<<<4096, 256, 0, stream>>>(W_res, wbig, NRES * NRES);                  // Wbig[0:2048]
  k_cast<<<64,   256, 0, stream>>>(We2, we2h, HDIM * HDIM);
  k_cast<<<1024, 256, 0, stream>>>(We3, we3h, NRES * HDIM);
  k_batt<<<NRES, 256, 0, stream>>>(Wproj, bv, bproj, bias_big);
  k_gemm1<<<dim3(32, 32), 256, 0, stream>>>(Wproj, Wv, wbig);                  // Wbig[2048:4096]
  k_bh1<<<HDIM, 256, 0, stream>>>(We1, be1, bias_big);
  k_gemm2<<<dim3(32, 2), 256, 0, stream>>>(We1, wbig);                         // Wbig[4096:4224]

  k_main<<<NBLK, 256, 0, stream>>>(x, W_in, ln_g, ln_b, be2, be3,
                                   w_mu, w_rho, b_mu, b_rho, w_eps, b_eps,
                                   wbig, bias_big, we2h, we3h, s16, yp, cnt, out);
}

// Round 2
// 8420.608 us; speedup vs baseline: 4.2045x; 4.2045x over previous
//
#include <hip/hip_runtime.h>
#include <hip/hip_fp16.h>
#include <cstdint>
#include <cstddef>

typedef _Float16 f16x8 __attribute__((ext_vector_type(8)));
typedef float    f32x4 __attribute__((ext_vector_type(4)));

#define MFMA(A,B,C) __builtin_amdgcn_mfma_f32_16x16x32_f16((A),(B),(C),0,0,0)

// ---- problem constants ----
#define NRES  2048
#define DIN   32
#define DOUT  16
#define HDIM  128
#define BBATCH 64
#define TSTEPS 256
#define WCOLS 4224     // 2048 (W_res) + 2048 (W_att) + 128 (W_h1)
#define NBLK  264      // 264 strips of 16 cols; blocks 0..255 also own S3 tiles
#define LEAF  33       // 264 / 8 leaves

// ---- workspace layout (bytes) ----
#define OFF_WBIG  ((size_t)0)          // 4224*2048 f16   = 17,301,504
#define OFF_BIAS  ((size_t)17301504)   // 4224 f32        =     16,896
#define OFF_WE2H  ((size_t)17318400)   // 128*128 f16     =     32,768
#define OFF_WE3H  ((size_t)17351168)   // 2048*128 f16    =    524,288
#define OFF_S16   ((size_t)17875456)   // 64*2048 f16     =    262,144
#define OFF_YP    ((size_t)18137600)   // 64*4224 f32     =  1,081,344
#define OFF_CNT   ((size_t)19219200)   // counters (1 KB)
// total ~19.2 MB

__device__ __forceinline__ float gelu_exact(float v) {
  return 0.5f * v * (1.0f + erff(v * 0.70710678118654752f));
}

// sc1-bypass stores: data goes straight to the device coherence point; L2 stays clean
__device__ __forceinline__ void stg_f32(float* p, float v) {
  __hip_atomic_store((unsigned*)p, __builtin_bit_cast(unsigned, v),
                     __ATOMIC_RELAXED, __HIP_MEMORY_SCOPE_AGENT);
}
__device__ __forceinline__ void stg_f16(_Float16* p, _Float16 v) {
  __hip_atomic_store((unsigned short*)p, __builtin_bit_cast(unsigned short, v),
                     __ATOMIC_RELAXED, __HIP_MEMORY_SCOPE_AGENT);
}

// ---------------- prep kernels (unchanged from round 1, verified) ----------------

__global__ void k_cast(const float* __restrict__ src, _Float16* __restrict__ dst, int n) {
  int i = blockIdx.x * blockDim.x + threadIdx.x;
  int stride = gridDim.x * blockDim.x;
  for (; i < n; i += stride) dst[i] = (_Float16)src[i];
}

__global__ void k_batt(const float* __restrict__ Wproj, const float* __restrict__ bv,
                       const float* __restrict__ bproj, float* __restrict__ bias_big) {
  int c = blockIdx.x, tid = threadIdx.x;
  float p = 0.f;
  for (int k = tid; k < NRES; k += 256) p += Wproj[(size_t)c * NRES + k] * bv[k];
  for (int m = 1; m < 64; m <<= 1) p += __shfl_xor(p, m);
  __shared__ float r4[4];
  if ((tid & 63) == 0) r4[tid >> 6] = p;
  __syncthreads();
  if (tid == 0) bias_big[2048 + c] = r4[0] + r4[1] + r4[2] + r4[3] + bproj[c];
}

__global__ void k_bh1(const float* __restrict__ We1, const float* __restrict__ be1,
                      float* __restrict__ bias_big) {
  int h = blockIdx.x, tid = threadIdx.x;
  float p = 0.f;
  for (int n = tid; n < NRES; n += 256) p += We1[(size_t)h * NRES + n] * bias_big[2048 + n];
  for (int m = 1; m < 64; m <<= 1) p += __shfl_xor(p, m);
  __shared__ float r4[4];
  if ((tid & 63) == 0) r4[tid >> 6] = p;
  __syncthreads();
  if (tid == 0) bias_big[4096 + h] = r4[0] + r4[1] + r4[2] + r4[3] + be1[h];
}

__global__ void __launch_bounds__(256) k_gemm1(const float* __restrict__ Wproj,
                                               const float* __restrict__ Wv,
                                               _Float16* __restrict__ wbig) {
  __shared__ _Float16 BT[64][40];
  const int kblock = blockIdx.x, cblock = blockIdx.y;
  const int tid = threadIdx.x, wv = tid >> 6, lane = tid & 63;
  const int l4 = lane >> 4, l15 = lane & 15;
  const int crow0 = cblock * 64 + wv * 16;
  f32x4 acc[4];
  f32x4 zero = {0.f, 0.f, 0.f, 0.f};
  for (int i = 0; i < 4; ++i) acc[i] = zero;

  for (int mc = 0; mc < 64; ++mc) {
    const int m0 = mc * 32;
    {
      int m = tid >> 3, kk = (tid & 7) * 8;
      const float* src = &Wv[(size_t)(m0 + m) * NRES + kblock * 64 + kk];
      float4 v0 = *(const float4*)src;
      float4 v1 = *(const float4*)(src + 4);
      float tmp[8] = {v0.x, v0.y, v0.z, v0.w, v1.x, v1.y, v1.z, v1.w};
      #pragma unroll
      for (int j = 0; j < 8; ++j) BT[kk + j][m] = (_Float16)tmp[j];
    }
    __syncthreads();
    const float* pa = &Wproj[(size_t)(crow0 + l15) * NRES + m0 + l4 * 8];
    float4 a0 = *(const float4*)pa;
    float4 a1 = *(const float4*)(pa + 4);
    f16x8 af;
    af[0]=(_Float16)a0.x; af[1]=(_Float16)a0.y; af[2]=(_Float16)a0.z; af[3]=(_Float16)a0.w;
    af[4]=(_Float16)a1.x; af[5]=(_Float16)a1.y; af[6]=(_Float16)a1.z; af[7]=(_Float16)a1.w;
    #pragma unroll
    for (int kt = 0; kt < 4; ++kt) {
      f16x8 bf = *(const f16x8*)&BT[kt * 16 + l15][l4 * 8];
      acc[kt] = MFMA(af, bf, acc[kt]);
    }
    __syncthreads();
  }
  #pragma unroll
  for (int kt = 0; kt < 4; ++kt)
    #pragma unroll
    for (int i = 0; i < 4; ++i) {
      int c = crow0 + l4 * 4 + i;
      int k = kblock * 64 + kt * 16 + l15;
      wbig[(size_t)(2048 + c) * NRES + k] = (_Float16)acc[kt][i];
    }
}

__global__ void __launch_bounds__(256) k_gemm2(const float* __restrict__ We1,
                                               _Float16* __restrict__ wbig) {
  __shared__ _Float16 BT[64][40];
  const int kblock = blockIdx.x, hblock = blockIdx.y;
  const int tid = threadIdx.x, wv = tid >> 6, lane = tid & 63;
  const int l4 = lane >> 4, l15 = lane & 15;
  const int hrow0 = hblock * 64 + wv * 16;
  f32x4 acc[4];
  f32x4 zero = {0.f, 0.f, 0.f, 0.f};
  for (int i = 0; i < 4; ++i) acc[i] = zero;

  for (int nc = 0; nc < 64; ++nc) {
    const int n0 = nc * 32;
    {
      int n = tid >> 3, kk = (tid & 7) * 8;
      f16x8 v = *(const f16x8*)&wbig[(size_t)(2048 + n0 + n) * NRES + kblock * 64 + kk];
      #pragma unroll
      for (int j = 0; j < 8; ++j) BT[kk + j][n] = v[j];
    }
    __syncthreads();
    const float* pa = &We1[(size_t)(hrow0 + l15) * NRES + n0 + l4 * 8];
    float4 a0 = *(const float4*)pa;
    float4 a1 = *(const float4*)(pa + 4);
    f16x8 af;
    af[0]=(_Float16)a0.x; af[1]=(_Float16)a0.y; af[2]=(_Float16)a0.z; af[3]=(_Float16)a0.w;
    af[4]=(_Float16)a1.x; af[5]=(_Float16)a1.y; af[6]=(_Float16)a1.z; af[7]=(_Float16)a1.w;
    #pragma unroll
    for (int kt = 0; kt < 4; ++kt) {
      f16x8 bf = *(const f16x8*)&BT[kt * 16 + l15][l4 * 8];
      acc[kt] = MFMA(af, bf, acc[kt]);
    }
    __syncthreads();
  }
  #pragma unroll
  for (int kt = 0; kt < 4; ++kt)
    #pragma unroll
    for (int i = 0; i < 4; ++i) {
      int h = hrow0 + l4 * 4 + i;
      int k = kblock * 64 + kt * 16 + l15;
      wbig[(size_t)(4096 + h) * NRES + k] = (_Float16)acc[kt][i];
    }
}

// ---------------- hierarchical device barrier ----------------
// cbase layout (unsigned): leaf j at [j*16], root at [128], epoch at [144].
// Monotonic targets: leaf -> phase*LEAF, root -> phase*8, epoch -> phase.
__device__ __forceinline__ void gbar2(unsigned* cbase, int b, unsigned phase) {
  // all waves drain their own vmem (sc1 store write-acks) before arriving
  asm volatile("s_waitcnt vmcnt(0)" ::: "memory");
  __syncthreads();
  if (threadIdx.x == 0) {
    unsigned* leaf = cbase + (b & 7) * 16;
    unsigned old = __hip_atomic_fetch_add(leaf, 1u, __ATOMIC_RELAXED, __HIP_MEMORY_SCOPE_AGENT);
    if (old == phase * (unsigned)LEAF - 1u) {
      unsigned r = __hip_atomic_fetch_add(cbase + 128, 1u, __ATOMIC_RELAXED, __HIP_MEMORY_SCOPE_AGENT);
      if (r == phase * 8u - 1u)
        __hip_atomic_store(cbase + 144, phase, __ATOMIC_RELAXED, __HIP_MEMORY_SCOPE_AGENT);
    }
    unsigned spins = 0;
    while (__hip_atomic_load(cbase + 144, __ATOMIC_RELAXED, __HIP_MEMORY_SCOPE_AGENT) < phase) {
      __builtin_amdgcn_s_sleep(2);
      if (++spins > (1u << 14)) break;  // safety bail: wrong answer, not hang
    }
    // acquire: invalidates this CU's L1 + this XCD's L2 (clean lines only -> cheap)
    (void)__hip_atomic_load(cbase + 144, __ATOMIC_ACQUIRE, __HIP_MEMORY_SCOPE_AGENT);
  }
  __syncthreads();
}

// ---------------- main persistent kernel ----------------

__global__ void __launch_bounds__(256, 2) k_main(
    const float* __restrict__ x, const float* __restrict__ W_in,
    const float* __restrict__ ln_g, const float* __restrict__ ln_b,
    const float* __restrict__ be2v, const float* __restrict__ be3v,
    const float* __restrict__ w_mu, const float* __restrict__ w_rho,
    const float* __restrict__ b_mu, const float* __restrict__ b_rho,
    const float* __restrict__ w_eps, const float* __restrict__ b_eps,
    const _Float16* __restrict__ wbig, const float* __restrict__ bias_big,
    const _Float16* __restrict__ we2h, const _Float16* __restrict__ we3h,
    _Float16* s16, float* yp,
    unsigned* cnt, float* __restrict__ out)
{
  const int b = blockIdx.x, tid = threadIdx.x;
  const int wv = tid >> 6, lane = tid & 63;
  const int l4 = lane >> 4, l15 = lane & 15;

  __shared__ float    lds_red[4][64][17];   // S1 K-split reduce (17.4 KB)
  __shared__ _Float16 lds_w2[128][136];     // We2 resident (34.8 KB)
  __shared__ _Float16 lds_h1[16][136];      // gelu(LN(h1)) for this block's 16 rows
  __shared__ _Float16 lds_g2[16][136];      // gelu(h2)
  __shared__ float    lds_x[16][33];        // x_t rows

  // ---- S1 identity: strip b (16 cols of Wbig), full K=2048, 4-wave K-split ----
  const int strip = b;
  f16x8 Bf[16];
  #pragma unroll
  for (int ks = 0; ks < 16; ++ks)
    Bf[ks] = *(const f16x8*)&wbig[(size_t)(strip * 16 + l15) * NRES + wv * 512 + ks * 32 + l4 * 8];

  // ---- S3 identity: blocks 0..255 own 16 rows x 32 cols of the state ----
  const bool doS3 = (b < 256);
  const int R0 = (b >> 6) * 16, C0 = (b & 63) * 32;

  float g8[8], bb8[8], bh8[8];
  #pragma unroll
  for (int jj = 0; jj < 8; ++jj) {
    g8[jj]  = ln_g[l15 + 16 * jj];
    bb8[jj] = ln_b[l15 + 16 * jj];
    bh8[jj] = bias_big[4096 + l15 + 16 * jj];
  }
  float be2r[2];
  #pragma unroll
  for (int ct = 0; ct < 2; ++ct) be2r[ct] = be2v[(wv * 2 + ct) * 16 + l15];

  // waves 0,1 handle the update of cols C0+wv*16+l15
  const int mycol = C0 + wv * 16 + l15;
  f16x8 We3f[4];
  float be3r = 0.f, battr = 0.f, winr[32];
  if (doS3 && wv < 2) {
    #pragma unroll
    for (int ks = 0; ks < 4; ++ks)
      We3f[ks] = *(const f16x8*)&we3h[(size_t)mycol * HDIM + ks * 32 + l4 * 8];
    be3r  = be3v[mycol];
    battr = bias_big[2048 + mycol];
    #pragma unroll
    for (int k = 0; k < DIN; ++k) winr[k] = W_in[mycol * DIN + k];
  }

  // stage We2 into LDS once
  {
    int row = tid >> 1, half = tid & 1;
    #pragma unroll
    for (int j = 0; j < 8; ++j) {
      f16x8 v = *(const f16x8*)&we2h[(size_t)row * HDIM + half * 64 + j * 8];
      *(f16x8*)&lds_w2[row][half * 64 + j * 8] = v;
    }
  }
  __syncthreads();

  const f32x4 zero = {0.f, 0.f, 0.f, 0.f};
  unsigned phase = 0;

  for (int t = 0; t < TSTEPS; ++t) {
    // ===== S1: Y[:, strip] = s @ Wbig[strip].T, full K (4-wave K-split) =====
    f32x4 a0 = zero, a1 = zero, a2 = zero, a3 = zero;
    #pragma unroll
    for (int ks = 0; ks < 16; ++ks) {
      const int kk = wv * 512 + ks * 32 + l4 * 8;
      f16x8 A0 = *(const f16x8*)&s16[(size_t)(l15) * NRES + kk];
      f16x8 A1 = *(const f16x8*)&s16[(size_t)(16 + l15) * NRES + kk];
      f16x8 A2 = *(const f16x8*)&s16[(size_t)(32 + l15) * NRES + kk];
      f16x8 A3 = *(const f16x8*)&s16[(size_t)(48 + l15) * NRES + kk];
      a0 = MFMA(A0, Bf[ks], a0);
      a1 = MFMA(A1, Bf[ks], a1);
      a2 = MFMA(A2, Bf[ks], a2);
      a3 = MFMA(A3, Bf[ks], a3);
    }
    #pragma unroll
    for (int i = 0; i < 4; ++i) {
      lds_red[wv][lane][0 + i]  = a0[i];
      lds_red[wv][lane][4 + i]  = a1[i];
      lds_red[wv][lane][8 + i]  = a2[i];
      lds_red[wv][lane][12 + i] = a3[i];
    }
    __syncthreads();
    // wave wv reduces row-tile q=wv and writes yp (sc1-bypass stores)
    #pragma unroll
    for (int i = 0; i < 4; ++i) {
      float s = lds_red[0][lane][wv * 4 + i] + lds_red[1][lane][wv * 4 + i]
              + lds_red[2][lane][wv * 4 + i] + lds_red[3][lane][wv * 4 + i];
      stg_f32(&yp[(size_t)(wv * 16 + l4 * 4 + i) * WCOLS + strip * 16 + l15], s);
    }
    ++phase;
    gbar2(cnt, b, phase);

    // ===== S3: LN -> GELU -> We2 -> GELU -> We3 -> state update =====
    if (doS3) {
      { // stage x_t (16 rows x 32)
        int xr = tid >> 4, k0 = tid & 15;
        lds_x[xr][k0]      = x[((size_t)(R0 + xr) * TSTEPS + t) * DIN + k0];
        lds_x[xr][k0 + 16] = x[((size_t)(R0 + xr) * TSTEPS + t) * DIN + k0 + 16];
      }
      // h1 + bias, LayerNorm over 128, exact GELU (row lr = wv*4+l4)
      const int lr = wv * 4 + l4;
      float h1v[8], s1 = 0.f, s2 = 0.f;
      const size_t yb = (size_t)(R0 + lr) * WCOLS + 4096;
      #pragma unroll
      for (int jj = 0; jj < 8; ++jj) {
        float v = yp[yb + l15 + 16 * jj] + bh8[jj];
        h1v[jj] = v; s1 += v; s2 += v * v;
      }
      #pragma unroll
      for (int m = 1; m < 16; m <<= 1) { s1 += __shfl_xor(s1, m); s2 += __shfl_xor(s2, m); }
      const float mu = s1 * (1.f / 128.f);
      const float var = s2 * (1.f / 128.f) - mu * mu;
      const float rs = rsqrtf(var + 1e-5f);
      #pragma unroll
      for (int jj = 0; jj < 8; ++jj) {
        float hn = (h1v[jj] - mu) * rs * g8[jj] + bb8[jj];
        lds_h1[lr][l15 + 16 * jj] = (_Float16)gelu_exact(hn);
      }
      __syncthreads();
      // h2 = gelu(h1g @ We2^T + be2): wave wv does col-tiles ctg = wv*2, wv*2+1
      f32x4 c0 = zero, c1 = zero;
      #pragma unroll
      for (int ks = 0; ks < 4; ++ks) {
        f16x8 af = *(const f16x8*)&lds_h1[l15][ks * 32 + l4 * 8];
        f16x8 b0 = *(const f16x8*)&lds_w2[(wv * 2 + 0) * 16 + l15][ks * 32 + l4 * 8];
        f16x8 b1 = *(const f16x8*)&lds_w2[(wv * 2 + 1) * 16 + l15][ks * 32 + l4 * 8];
        c0 = MFMA(af, b0, c0);
        c1 = MFMA(af, b1, c1);
      }
      #pragma unroll
      for (int i = 0; i < 4; ++i) {
        int rr = l4 * 4 + i;
        lds_g2[rr][(wv * 2 + 0) * 16 + l15] = (_Float16)gelu_exact(c0[i] + be2r[0]);
        lds_g2[rr][(wv * 2 + 1) * 16 + l15] = (_Float16)gelu_exact(c1[i] + be2r[1]);
      }
      __syncthreads();
      // phys + state update: waves 0,1 own cols C0..C0+31
      if (wv < 2) {
        f32x4 accp = zero;
        #pragma unroll
        for (int ks = 0; ks < 4; ++ks) {
          f16x8 af = *(const f16x8*)&lds_g2[l15][ks * 32 + l4 * 8];
          accp = MFMA(af, We3f[ks], accp);
        }
        #pragma unroll
        for (int i = 0; i < 4; ++i) {
          int r2 = l4 * 4 + i, grow = R0 + r2;
          float satt = yp[(size_t)grow * WCOLS + 2048 + mycol] + battr;
          float rrv  = yp[(size_t)grow * WCOLS + mycol];
          float inp = 0.f;
          #pragma unroll
          for (int k = 0; k < DIN; ++k) inp += lds_x[r2][k] * winr[k];
          float ns = 0.7f * satt + 0.3f * tanhf(inp + rrv + accp[i] + be3r);
          stg_f16(&s16[(size_t)grow * NRES + mycol], (_Float16)ns);
        }
      }
    }
    ++phase;
    gbar2(cnt, b, phase);
  }

  // ---- Bayesian output head (blocks 0..63, after final barrier+acquire) ----
  if (b < BBATCH) {
    float* red = &lds_red[0][0][0];
    int o = tid >> 4, sg = tid & 15;
    float p = 0.f;
    for (int n = sg * 128; n < sg * 128 + 128; ++n) {
      float sv = (float)s16[(size_t)b * NRES + n];
      float w = w_mu[(size_t)o * NRES + n]
              + log1pf(expf(w_rho[(size_t)o * NRES + n])) * w_eps[(size_t)o * NRES + n];
      p += sv * w;
    }
    red[o * 17 + sg] = p;
    __syncthreads();
    if (tid < DOUT) {
      float sum = 0.f;
      for (int q = 0; q < 16; ++q) sum += red[tid * 17 + q];
      float bs = b_mu[tid] + log1pf(expf(b_rho[tid])) * b_eps[tid];
      out[b * DOUT + tid] = sum + bs;
    }
  }
}

// ---------------- host ----------------

extern "C" void kernel_launch(void* const* d_in, const int* in_sizes, int n_in,
                              void* d_out, int out_size, void* d_ws, size_t ws_size,
                              hipStream_t stream) {
  (void)in_sizes; (void)n_in; (void)out_size; (void)ws_size;
  const float* x     = (const float*)d_in[0];
  const float* W_in  = (const float*)d_in[1];
  const float* W_res = (const float*)d_in[2];
  const float* Wv    = (const float*)d_in[3];
  const float* bv    = (const float*)d_in[4];
  const float* Wproj = (const float*)d_in[5];
  const float* bproj = (const float*)d_in[6];
  const float* We1   = (const float*)d_in[7];
  const float* be1   = (const float*)d_in[8];
  const float* ln_g  = (const float*)d_in[9];
  const float* ln_b  = (const float*)d_in[10];
  const float* We2   = (const float*)d_in[11];
  const float* be2   = (const float*)d_in[12];
  const float* We3   = (const float*)d_in[13];
  const float* be3   = (const float*)d_in[14];
  const float* w_mu  = (const float*)d_in[15];
  const float* w_rho = (const float*)d_in[16];
  const float* b_mu  = (const float*)d_in[17];
  const float* b_rho = (const float*)d_in[18];
  const float* w_eps = (const float*)d_in[19];
  const float* b_eps = (const float*)d_in[20];
  float* out = (float*)d_out;

  char* ws = (char*)d_ws;
  _Float16* wbig     = (_Float16*)(ws + OFF_WBIG);
  float*    bias_big = (float*)(ws + OFF_BIAS);
  _Float16* we2h     = (_Float16*)(ws + OFF_WE2H);
  _Float16* we3h     = (_Float16*)(ws + OFF_WE3H);
  _Float16* s16      = (_Float16*)(ws + OFF_S16);
  float*    yp       = (float*)(ws + OFF_YP);
  unsigned* cnt      = (unsigned*)(ws + OFF_CNT);

  hipMemsetAsync(bias_big, 0, WCOLS * sizeof(float), stream);
  hipMemsetAsync(s16, 0, (size_t)BBATCH * NRES * sizeof(_Float16), stream);
  hipMemsetAsync(cnt, 0, 1024, stream);

  k_cast<<<4096, 256, 0, stream>>>(W_res, wbig, NRES * NRES);                  // Wbig[0:2048]
  k_cast<<<64,   256, 0, stream>>>(We2, we2h, HDIM * HDIM);
  k_cast<<<1024, 256, 0, stream>>>(We3, we3h, NRES * HDIM);
  k_batt<<<NRES, 256, 0, stream>>>(Wproj, bv, bproj, bias_big);
  k_gemm1<<<dim3(32, 32), 256, 0, stream>>>(Wproj, Wv, wbig);                  // Wbig[2048:4096]
  k_bh1<<<HDIM, 256, 0, stream>>>(We1, be1, bias_big);
  k_gemm2<<<dim3(32, 2), 256, 0, stream>>>(We1, wbig);                         // Wbig[4096:4224]

  k_main<<<NBLK, 256, 0, stream>>>(x, W_in, ln_g, ln_b, be2, be3,
                                   w_mu, w_rho, b_mu, b_rho, w_eps, b_eps,
                                   wbig, bias_big, we2h, we3h, s16, yp, cnt, out);
}

// Round 3
// 7289.886 us; speedup vs baseline: 4.8566x; 1.1551x over previous
//
#include <hip/hip_runtime.h>
#include <hip/hip_fp16.h>
#include <cstdint>
#include <cstddef>

typedef _Float16 f16x8 __attribute__((ext_vector_type(8)));
typedef float    f32x4 __attribute__((ext_vector_type(4)));

#define MFMA(A,B,C) __builtin_amdgcn_mfma_f32_16x16x32_f16((A),(B),(C),0,0,0)

// ---- problem constants ----
#define NRES  2048
#define DIN   32
#define DOUT  16
#define HDIM  128
#define BBATCH 64
#define TSTEPS 256
#define WCOLS 4224     // 2048 (W_res) + 2048 (W_att) + 128 (W_h1)
#define NBLK_W 264     // worker blocks: 264 strips of 16 cols; 0..255 also own S3 tiles
#define NBLK  265      // + 1 collector block

// ---- workspace layout (bytes) ----
#define OFF_WBIG  ((size_t)0)          // 4224*2048 f16   = 17,301,504
#define OFF_BIAS  ((size_t)17301504)   // 4224 f32        =     16,896
#define OFF_WE2H  ((size_t)17318400)   // 128*128 f16     =     32,768
#define OFF_WE3H  ((size_t)17351168)   // 2048*128 f16    =    524,288
#define OFF_S16   ((size_t)17875456)   // 64*2048 f16     =    262,144
#define OFF_YP    ((size_t)18137600)   // 64*4224 f32     =  1,081,344
#define OFF_WINH  ((size_t)19219200)   // 2048*32 f16     =    131,072
#define OFF_CNT   ((size_t)19350272)   // slots (320 u32) + wake lines (264*64 B)
// total ~19.37 MB

__device__ __forceinline__ float gelu_exact(float v) {
  return 0.5f * v * (1.0f + erff(v * 0.70710678118654752f));
}

// sc1-bypass stores: data goes straight to the device coherence point; L2 stays clean
__device__ __forceinline__ void stg_f32(float* p, float v) {
  __hip_atomic_store((unsigned*)p, __builtin_bit_cast(unsigned, v),
                     __ATOMIC_RELAXED, __HIP_MEMORY_SCOPE_AGENT);
}
__device__ __forceinline__ void stg_f16(_Float16* p, _Float16 v) {
  __hip_atomic_store((unsigned short*)p, __builtin_bit_cast(unsigned short, v),
                     __ATOMIC_RELAXED, __HIP_MEMORY_SCOPE_AGENT);
}

// ---------------- prep kernels (verified rounds 1-2) ----------------

__global__ void k_cast(const float* __restrict__ src, _Float16* __restrict__ dst, int n) {
  int i = blockIdx.x * blockDim.x + threadIdx.x;
  int stride = gridDim.x * blockDim.x;
  for (; i < n; i += stride) dst[i] = (_Float16)src[i];
}

__global__ void k_batt(const float* __restrict__ Wproj, const float* __restrict__ bv,
                       const float* __restrict__ bproj, float* __restrict__ bias_big) {
  int c = blockIdx.x, tid = threadIdx.x;
  float p = 0.f;
  for (int k = tid; k < NRES; k += 256) p += Wproj[(size_t)c * NRES + k] * bv[k];
  for (int m = 1; m < 64; m <<= 1) p += __shfl_xor(p, m);
  __shared__ float r4[4];
  if ((tid & 63) == 0) r4[tid >> 6] = p;
  __syncthreads();
  if (tid == 0) bias_big[2048 + c] = r4[0] + r4[1] + r4[2] + r4[3] + bproj[c];
}

__global__ void k_bh1(const float* __restrict__ We1, const float* __restrict__ be1,
                      float* __restrict__ bias_big) {
  int h = blockIdx.x, tid = threadIdx.x;
  float p = 0.f;
  for (int n = tid; n < NRES; n += 256) p += We1[(size_t)h * NRES + n] * bias_big[2048 + n];
  for (int m = 1; m < 64; m <<= 1) p += __shfl_xor(p, m);
  __shared__ float r4[4];
  if ((tid & 63) == 0) r4[tid >> 6] = p;
  __syncthreads();
  if (tid == 0) bias_big[4096 + h] = r4[0] + r4[1] + r4[2] + r4[3] + be1[h];
}

__global__ void __launch_bounds__(256) k_gemm1(const float* __restrict__ Wproj,
                                               const float* __restrict__ Wv,
                                               _Float16* __restrict__ wbig) {
  __shared__ _Float16 BT[64][40];
  const int kblock = blockIdx.x, cblock = blockIdx.y;
  const int tid = threadIdx.x, wv = tid >> 6, lane = tid & 63;
  const int l4 = lane >> 4, l15 = lane & 15;
  const int crow0 = cblock * 64 + wv * 16;
  f32x4 acc[4];
  f32x4 zero = {0.f, 0.f, 0.f, 0.f};
  for (int i = 0; i < 4; ++i) acc[i] = zero;

  for (int mc = 0; mc < 64; ++mc) {
    const int m0 = mc * 32;
    {
      int m = tid >> 3, kk = (tid & 7) * 8;
      const float* src = &Wv[(size_t)(m0 + m) * NRES + kblock * 64 + kk];
      float4 v0 = *(const float4*)src;
      float4 v1 = *(const float4*)(src + 4);
      float tmp[8] = {v0.x, v0.y, v0.z, v0.w, v1.x, v1.y, v1.z, v1.w};
      #pragma unroll
      for (int j = 0; j < 8; ++j) BT[kk + j][m] = (_Float16)tmp[j];
    }
    __syncthreads();
    const float* pa = &Wproj[(size_t)(crow0 + l15) * NRES + m0 + l4 * 8];
    float4 a0 = *(const float4*)pa;
    float4 a1 = *(const float4*)(pa + 4);
    f16x8 af;
    af[0]=(_Float16)a0.x; af[1]=(_Float16)a0.y; af[2]=(_Float16)a0.z; af[3]=(_Float16)a0.w;
    af[4]=(_Float16)a1.x; af[5]=(_Float16)a1.y; af[6]=(_Float16)a1.z; af[7]=(_Float16)a1.w;
    #pragma unroll
    for (int kt = 0; kt < 4; ++kt) {
      f16x8 bf = *(const f16x8*)&BT[kt * 16 + l15][l4 * 8];
      acc[kt] = MFMA(af, bf, acc[kt]);
    }
    __syncthreads();
  }
  #pragma unroll
  for (int kt = 0; kt < 4; ++kt)
    #pragma unroll
    for (int i = 0; i < 4; ++i) {
      int c = crow0 + l4 * 4 + i;
      int k = kblock * 64 + kt * 16 + l15;
      wbig[(size_t)(2048 + c) * NRES + k] = (_Float16)acc[kt][i];
    }
}

__global__ void __launch_bounds__(256) k_gemm2(const float* __restrict__ We1,
                                               _Float16* __restrict__ wbig) {
  __shared__ _Float16 BT[64][40];
  const int kblock = blockIdx.x, hblock = blockIdx.y;
  const int tid = threadIdx.x, wv = tid >> 6, lane = tid & 63;
  const int l4 = lane >> 4, l15 = lane & 15;
  const int hrow0 = hblock * 64 + wv * 16;
  f32x4 acc[4];
  f32x4 zero = {0.f, 0.f, 0.f, 0.f};
  for (int i = 0; i < 4; ++i) acc[i] = zero;

  for (int nc = 0; nc < 64; ++nc) {
    const int n0 = nc * 32;
    {
      int n = tid >> 3, kk = (tid & 7) * 8;
      f16x8 v = *(const f16x8*)&wbig[(size_t)(2048 + n0 + n) * NRES + kblock * 64 + kk];
      #pragma unroll
      for (int j = 0; j < 8; ++j) BT[kk + j][n] = v[j];
    }
    __syncthreads();
    const float* pa = &We1[(size_t)(hrow0 + l15) * NRES + n0 + l4 * 8];
    float4 a0 = *(const float4*)pa;
    float4 a1 = *(const float4*)(pa + 4);
    f16x8 af;
    af[0]=(_Float16)a0.x; af[1]=(_Float16)a0.y; af[2]=(_Float16)a0.z; af[3]=(_Float16)a0.w;
    af[4]=(_Float16)a1.x; af[5]=(_Float16)a1.y; af[6]=(_Float16)a1.z; af[7]=(_Float16)a1.w;
    #pragma unroll
    for (int kt = 0; kt < 4; ++kt) {
      f16x8 bf = *(const f16x8*)&BT[kt * 16 + l15][l4 * 8];
      acc[kt] = MFMA(af, bf, acc[kt]);
    }
    __syncthreads();
  }
  #pragma unroll
  for (int kt = 0; kt < 4; ++kt)
    #pragma unroll
    for (int i = 0; i < 4; ++i) {
      int h = hrow0 + l4 * 4 + i;
      int k = kblock * 64 + kt * 16 + l15;
      wbig[(size_t)(4096 + h) * NRES + k] = (_Float16)acc[kt][i];
    }
}

// ---------------- slot/wake barrier (collector-based, contention-free) ----------------
// slots: 320 u32 (264 live, 264..319 pre-set 0xFFFFFFFF). wake: 264 private 64B lines.
__device__ __forceinline__ void gbar3(unsigned* slots, unsigned* wake, int b, unsigned phase) {
  asm volatile("s_waitcnt vmcnt(0)" ::: "memory");   // every wave drains its sc1 stores
  __syncthreads();
  if (threadIdx.x == 0) {
    __hip_atomic_store(slots + b, phase, __ATOMIC_RELAXED, __HIP_MEMORY_SCOPE_AGENT);
    unsigned spins = 0;
    while (__hip_atomic_load(wake + (size_t)b * 16, __ATOMIC_RELAXED, __HIP_MEMORY_SCOPE_AGENT) < phase) {
      __builtin_amdgcn_s_sleep(1);
      if (++spins > (1u << 20)) break;   // safety bail: wrong answer, not hang
    }
    // acquire: invalidate this CU's L1 + XCD L2 (clean lines) so cached reads see fresh data
    (void)__hip_atomic_load(wake + (size_t)b * 16, __ATOMIC_ACQUIRE, __HIP_MEMORY_SCOPE_AGENT);
  }
  __syncthreads();
}

// ---------------- main persistent kernel ----------------

__global__ void __launch_bounds__(256, 2) k_main(
    const float* __restrict__ x,
    const float* __restrict__ ln_g, const float* __restrict__ ln_b,
    const float* __restrict__ be2v, const float* __restrict__ be3v,
    const float* __restrict__ w_mu, const float* __restrict__ w_rho,
    const float* __restrict__ b_mu, const float* __restrict__ b_rho,
    const float* __restrict__ w_eps, const float* __restrict__ b_eps,
    const _Float16* __restrict__ wbig, const float* __restrict__ bias_big,
    const _Float16* __restrict__ we2h, const _Float16* __restrict__ we3h,
    const _Float16* __restrict__ winh,
    _Float16* s16, float* yp,
    unsigned* cnt, float* __restrict__ out)
{
  const int b = blockIdx.x, tid = threadIdx.x;
  unsigned* slots = cnt;          // 320 u32
  unsigned* wake  = cnt + 512;    // 264 lines, stride 16 u32 (64 B)

  // ===== collector block: sweeps slots, broadcasts per-block wake lines =====
  if (b == NBLK_W) {
    if (tid >= 64) return;
    for (unsigned p = 1; p <= 2u * TSTEPS; ++p) {
      unsigned spins = 0;
      for (;;) {
        bool ok = true;
        #pragma unroll
        for (int j = 0; j < 5; ++j) {
          unsigned v = __hip_atomic_load(slots + tid + j * 64, __ATOMIC_RELAXED, __HIP_MEMORY_SCOPE_AGENT);
          ok = ok && (v >= p);
        }
        if (__all((int)ok)) break;
        if (++spins > (1u << 19)) break;  // safety bail
        __builtin_amdgcn_s_sleep(1);
      }
      #pragma unroll
      for (int j = 0; j < 5; ++j) {
        int blk = tid + j * 64;
        if (blk < NBLK_W)
          __hip_atomic_store(wake + (size_t)blk * 16, p, __ATOMIC_RELAXED, __HIP_MEMORY_SCOPE_AGENT);
      }
    }
    return;
  }

  const int wv = tid >> 6, lane = tid & 63;
  const int l4 = lane >> 4, l15 = lane & 15;

  __shared__ float    lds_red[4][64][17];   // S1 K-split reduce (17.4 KB)
  __shared__ _Float16 lds_w2[128][136];     // We2 resident (34.8 KB)
  __shared__ _Float16 lds_h1[16][136];      // gelu(LN(h1)) for this block's 16 rows
  __shared__ _Float16 lds_g2[16][136];      // gelu(h2)
  __shared__ _Float16 lds_x[16][40];        // x_t rows (f16)

  // ---- S1 identity: strip b (16 cols of Wbig), full K=2048, 4-wave K-split ----
  const int strip = b;
  f16x8 Bf[16];
  #pragma unroll
  for (int ks = 0; ks < 16; ++ks)
    Bf[ks] = *(const f16x8*)&wbig[(size_t)(strip * 16 + l15) * NRES + wv * 512 + ks * 32 + l4 * 8];

  // ---- S3 identity: blocks 0..255 own 16 rows x 32 cols of the state ----
  const bool doS3 = (b < 256);
  const int R0 = (b >> 6) * 16, C0 = (b & 63) * 32;

  float g8[8], bb8[8], bh8[8];
  #pragma unroll
  for (int jj = 0; jj < 8; ++jj) {
    g8[jj]  = ln_g[l15 + 16 * jj];
    bb8[jj] = ln_b[l15 + 16 * jj];
    bh8[jj] = bias_big[4096 + l15 + 16 * jj];
  }
  float be2r[2];
  #pragma unroll
  for (int ct = 0; ct < 2; ++ct) be2r[ct] = be2v[(wv * 2 + ct) * 16 + l15];

  // waves 0,1 handle the update of cols C0+wv*16+l15
  const int mycol = C0 + wv * 16 + l15;
  f16x8 We3f[4];
  f16x8 Winf;                     // W_in fragment (K=32 exactly -> one MFMA)
  float be3r = 0.f, battr = 0.f;
  if (doS3 && wv < 2) {
    #pragma unroll
    for (int ks = 0; ks < 4; ++ks)
      We3f[ks] = *(const f16x8*)&we3h[(size_t)mycol * HDIM + ks * 32 + l4 * 8];
    be3r  = be3v[mycol];
    battr = bias_big[2048 + mycol];
    Winf  = *(const f16x8*)&winh[(size_t)mycol * DIN + l4 * 8];
  }

  // stage We2 into LDS once
  {
    int row = tid >> 1, half = tid & 1;
    #pragma unroll
    for (int j = 0; j < 8; ++j) {
      f16x8 v = *(const f16x8*)&we2h[(size_t)row * HDIM + half * 64 + j * 8];
      *(f16x8*)&lds_w2[row][half * 64 + j * 8] = v;
    }
  }
  __syncthreads();

  const f32x4 zero = {0.f, 0.f, 0.f, 0.f};
  unsigned phase = 0;

  for (int t = 0; t < TSTEPS; ++t) {
    // ===== S1: Y[:, strip] = s @ Wbig[strip].T, full K (4-wave K-split) =====
    f32x4 a0 = zero, a1 = zero, a2 = zero, a3 = zero;
    #pragma unroll
    for (int ks = 0; ks < 16; ++ks) {
      const int kk = wv * 512 + ks * 32 + l4 * 8;
      f16x8 A0 = *(const f16x8*)&s16[(size_t)(l15) * NRES + kk];
      f16x8 A1 = *(const f16x8*)&s16[(size_t)(16 + l15) * NRES + kk];
      f16x8 A2 = *(const f16x8*)&s16[(size_t)(32 + l15) * NRES + kk];
      f16x8 A3 = *(const f16x8*)&s16[(size_t)(48 + l15) * NRES + kk];
      a0 = MFMA(A0, Bf[ks], a0);
      a1 = MFMA(A1, Bf[ks], a1);
      a2 = MFMA(A2, Bf[ks], a2);
      a3 = MFMA(A3, Bf[ks], a3);
    }
    #pragma unroll
    for (int i = 0; i < 4; ++i) {
      lds_red[wv][lane][0 + i]  = a0[i];
      lds_red[wv][lane][4 + i]  = a1[i];
      lds_red[wv][lane][8 + i]  = a2[i];
      lds_red[wv][lane][12 + i] = a3[i];
    }
    __syncthreads();
    // wave wv reduces row-tile q=wv and writes yp (sc1-bypass stores)
    #pragma unroll
    for (int i = 0; i < 4; ++i) {
      float s = lds_red[0][lane][wv * 4 + i] + lds_red[1][lane][wv * 4 + i]
              + lds_red[2][lane][wv * 4 + i] + lds_red[3][lane][wv * 4 + i];
      stg_f32(&yp[(size_t)(wv * 16 + l4 * 4 + i) * WCOLS + strip * 16 + l15], s);
    }
    ++phase;
    gbar3(slots, wake, b, phase);

    // ===== S3: LN -> GELU -> We2 -> GELU -> We3 -> state update =====
    if (doS3) {
      { // stage x_t (16 rows x 32) as f16
        int xr = tid >> 4, k0 = (tid & 15) * 2;
        const float* xs = &x[((size_t)(R0 + xr) * TSTEPS + t) * DIN + k0];
        lds_x[xr][k0]     = (_Float16)xs[0];
        lds_x[xr][k0 + 1] = (_Float16)xs[1];
      }
      // h1 + bias, LayerNorm over 128, exact GELU (row lr = wv*4+l4)
      const int lr = wv * 4 + l4;
      float h1v[8], s1 = 0.f, s2 = 0.f;
      const size_t yb = (size_t)(R0 + lr) * WCOLS + 4096;
      #pragma unroll
      for (int jj = 0; jj < 8; ++jj) {
        float v = yp[yb + l15 + 16 * jj] + bh8[jj];
        h1v[jj] = v; s1 += v; s2 += v * v;
      }
      #pragma unroll
      for (int m = 1; m < 16; m <<= 1) { s1 += __shfl_xor(s1, m); s2 += __shfl_xor(s2, m); }
      const float mu = s1 * (1.f / 128.f);
      const float var = s2 * (1.f / 128.f) - mu * mu;
      const float rs = rsqrtf(var + 1e-5f);
      #pragma unroll
      for (int jj = 0; jj < 8; ++jj) {
        float hn = (h1v[jj] - mu) * rs * g8[jj] + bb8[jj];
        lds_h1[lr][l15 + 16 * jj] = (_Float16)gelu_exact(hn);
      }
      __syncthreads();
      // h2 = gelu(h1g @ We2^T + be2): wave wv does col-tiles wv*2, wv*2+1
      f32x4 c0 = zero, c1 = zero;
      #pragma unroll
      for (int ks = 0; ks < 4; ++ks) {
        f16x8 af = *(const f16x8*)&lds_h1[l15][ks * 32 + l4 * 8];
        f16x8 b0 = *(const f16x8*)&lds_w2[(wv * 2 + 0) * 16 + l15][ks * 32 + l4 * 8];
        f16x8 b1 = *(const f16x8*)&lds_w2[(wv * 2 + 1) * 16 + l15][ks * 32 + l4 * 8];
        c0 = MFMA(af, b0, c0);
        c1 = MFMA(af, b1, c1);
      }
      #pragma unroll
      for (int i = 0; i < 4; ++i) {
        int rr = l4 * 4 + i;
        lds_g2[rr][(wv * 2 + 0) * 16 + l15] = (_Float16)gelu_exact(c0[i] + be2r[0]);
        lds_g2[rr][(wv * 2 + 1) * 16 + l15] = (_Float16)gelu_exact(c1[i] + be2r[1]);
      }
      __syncthreads();
      // phys + input-term + state update: waves 0,1 own cols C0..C0+31
      if (wv < 2) {
        f32x4 accp = zero;
        #pragma unroll
        for (int ks = 0; ks < 4; ++ks) {
          f16x8 af = *(const f16x8*)&lds_g2[l15][ks * 32 + l4 * 8];
          accp = MFMA(af, We3f[ks], accp);
        }
        // input_term tile via one MFMA (K=32): A = x rows, B = W_in cols
        f16x8 ax = *(const f16x8*)&lds_x[l15][l4 * 8];
        f32x4 acci = MFMA(ax, Winf, zero);
        #pragma unroll
        for (int i = 0; i < 4; ++i) {
          int r2 = l4 * 4 + i, grow = R0 + r2;
          float satt = yp[(size_t)grow * WCOLS + 2048 + mycol] + battr;
          float rrv  = yp[(size_t)grow * WCOLS + mycol];
          float ns = 0.7f * satt + 0.3f * tanhf(acci[i] + rrv + accp[i] + be3r);
          stg_f16(&s16[(size_t)grow * NRES + mycol], (_Float16)ns);
        }
      }
    }
    ++phase;
    gbar3(slots, wake, b, phase);
  }

  // ---- Bayesian output head (blocks 0..63, after final barrier+acquire) ----
  if (b < BBATCH) {
    float* red = &lds_red[0][0][0];
    int o = tid >> 4, sg = tid & 15;
    float p = 0.f;
    for (int n = sg * 128; n < sg * 128 + 128; ++n) {
      float sv = (float)s16[(size_t)b * NRES + n];
      float w = w_mu[(size_t)o * NRES + n]
              + log1pf(expf(w_rho[(size_t)o * NRES + n])) * w_eps[(size_t)o * NRES + n];
      p += sv * w;
    }
    red[o * 17 + sg] = p;
    __syncthreads();
    if (tid < DOUT) {
      float sum = 0.f;
      for (int q = 0; q < 16; ++q) sum += red[tid * 17 + q];
      float bs = b_mu[tid] + log1pf(expf(b_rho[tid])) * b_eps[tid];
      out[b * DOUT + tid] = sum + bs;
    }
  }
}

// ---------------- host ----------------

extern "C" void kernel_launch(void* const* d_in, const int* in_sizes, int n_in,
                              void* d_out, int out_size, void* d_ws, size_t ws_size,
                              hipStream_t stream) {
  (void)in_sizes; (void)n_in; (void)out_size; (void)ws_size;
  const float* x     = (const float*)d_in[0];
  const float* W_in  = (const float*)d_in[1];
  const float* W_res = (const float*)d_in[2];
  const float* Wv    = (const float*)d_in[3];
  const float* bv    = (const float*)d_in[4];
  const float* Wproj = (const float*)d_in[5];
  const float* bproj = (const float*)d_in[6];
  const float* We1   = (const float*)d_in[7];
  const float* be1   = (const float*)d_in[8];
  const float* ln_g  = (const float*)d_in[9];
  const float* ln_b  = (const float*)d_in[10];
  const float* We2   = (const float*)d_in[11];
  const float* be2   = (const float*)d_in[12];
  const float* We3   = (const float*)d_in[13];
  const float* be3   = (const float*)d_in[14];
  const float* w_mu  = (const float*)d_in[15];
  const float* w_rho = (const float*)d_in[16];
  const float* b_mu  = (const float*)d_in[17];
  const float* b_rho = (const float*)d_in[18];
  const float* w_eps = (const float*)d_in[19];
  const float* b_eps = (const float*)d_in[20];
  float* out = (float*)d_out;

  char* ws = (char*)d_ws;
  _Float16* wbig     = (_Float16*)(ws + OFF_WBIG);
  float*    bias_big = (float*)(ws + OFF_BIAS);
  _Float16* we2h     = (_Float16*)(ws + OFF_WE2H);
  _Float16* we3h     = (_Float16*)(ws + OFF_WE3H);
  _Float16* s16      = (_Float16*)(ws + OFF_S16);
  float*    yp       = (float*)(ws + OFF_YP);
  _Float16* winh     = (_Float16*)(ws + OFF_WINH);
  unsigned* cnt      = (unsigned*)(ws + OFF_CNT);

  hipMemsetAsync(bias_big, 0, WCOLS * sizeof(float), stream);
  hipMemsetAsync(s16, 0, (size_t)BBATCH * NRES * sizeof(_Float16), stream);
  hipMemsetAsync(cnt, 0, 264 * 4, stream);                  // live slots = 0
  hipMemsetAsync((char*)cnt + 264 * 4, 0xFF, 56 * 4, stream); // pad slots = huge
  hipMemsetAsync(cnt + 512, 0, 264 * 64, stream);           // wake lines = 0

  k_cast<<<4096, 256, 0, stream>>>(W_res, wbig, NRES * NRES);                  // Wbig[0:2048]
  k_cast<<<64,   256, 0, stream>>>(We2, we2h, HDIM * HDIM);
  k_cast<<<1024, 256, 0, stream>>>(We3, we3h, NRES * HDIM);
  k_cast<<<256,  256, 0, stream>>>(W_in, winh, NRES * DIN);
  k_batt<<<NRES, 256, 0, stream>>>(Wproj, bv, bproj, bias_big);
  k_gemm1<<<dim3(32, 32), 256, 0, stream>>>(Wproj, Wv, wbig);                  // Wbig[2048:4096]
  k_bh1<<<HDIM, 256, 0, stream>>>(We1, be1, bias_big);
  k_gemm2<<<dim3(32, 2), 256, 0, stream>>>(We1, wbig);                         // Wbig[4096:4224]

  k_main<<<NBLK, 256, 0, stream>>>(x, ln_g, ln_b, be2, be3,
                                   w_mu, w_rho, b_mu, b_rho, w_eps, b_eps,
                                   wbig, bias_big, we2h, we3h, winh, s16, yp, cnt, out);
}

// Round 5
// 6629.723 us; speedup vs baseline: 5.3402x; 1.0996x over previous
//
#include <hip/hip_runtime.h>
#include <hip/hip_fp16.h>
#include <cstdint>
#include <cstddef>

typedef _Float16 f16x8 __attribute__((ext_vector_type(8)));
typedef float    f32x4 __attribute__((ext_vector_type(4)));

#define MFMA(A,B,C) __builtin_amdgcn_mfma_f32_16x16x32_f16((A),(B),(C),0,0,0)

// ---- problem constants ----
#define NRES  2048
#define DIN   32
#define DOUT  16
#define HDIM  128
#define BBATCH 64
#define TSTEPS 256
#define WCOLS 4224     // yp cols: 2048 res + 2048 att + 128 h1
#define NWORK 256      // worker blocks
#define NBLK  257      // + collector (co-resident: 2 blocks/CU guaranteed)

// ---- workspace layout (bytes) ----
#define OFF_WBIG  ((size_t)0)          // 4096*2048 f16  = 16,777,216 (res | att)
#define OFF_WH1   ((size_t)16777216)   // 128*2048 f16   =    524,288 -> 17,301,504
#define OFF_BIAS  ((size_t)17301504)   // 4224 f32       =     16,896 -> 17,318,400
#define OFF_WE2H  ((size_t)17318400)   // 128*128 f16    =     32,768 -> 17,351,168
#define OFF_WE3H  ((size_t)17351168)   // 2048*128 f16   =    524,288 -> 17,875,456
#define OFF_S16   ((size_t)17875456)   // 64*2048 f16    =    262,144 -> 18,137,600
#define OFF_YP    ((size_t)18137600)   // 64*4224 f32    =  1,081,344 -> 19,218,944
#define OFF_WINH  ((size_t)19219200)   // 2048*32 f16    =    131,072 -> 19,350,272
#define OFF_CNT   ((size_t)19350528)   // slots(256 u32, padded to 512) + wake(256 * 64B)

__device__ __forceinline__ float gelu_exact(float v) {
  return 0.5f * v * (1.0f + erff(v * 0.70710678118654752f));
}

// coalesced 16B write-through store (visible at device coherence point; L2 stays clean)
__device__ __forceinline__ void stg16(void* p, f32x4 v) {
  asm volatile("global_store_dwordx4 %0, %1, off sc0 sc1" :: "v"(p), "v"(v) : "memory");
}

// ---------------- prep kernels (verified rounds 1-3) ----------------

__global__ void k_cast(const float* __restrict__ src, _Float16* __restrict__ dst, int n) {
  int i = blockIdx.x * blockDim.x + threadIdx.x;
  int stride = gridDim.x * blockDim.x;
  for (; i < n; i += stride) dst[i] = (_Float16)src[i];
}

__global__ void k_batt(const float* __restrict__ Wproj, const float* __restrict__ bv,
                       const float* __restrict__ bproj, float* __restrict__ bias_big) {
  int c = blockIdx.x, tid = threadIdx.x;
  float p = 0.f;
  for (int k = tid; k < NRES; k += 256) p += Wproj[(size_t)c * NRES + k] * bv[k];
  for (int m = 1; m < 64; m <<= 1) p += __shfl_xor(p, m);
  __shared__ float r4[4];
  if ((tid & 63) == 0) r4[tid >> 6] = p;
  __syncthreads();
  if (tid == 0) bias_big[2048 + c] = r4[0] + r4[1] + r4[2] + r4[3] + bproj[c];
}

__global__ void k_bh1(const float* __restrict__ We1, const float* __restrict__ be1,
                      float* __restrict__ bias_big) {
  int h = blockIdx.x, tid = threadIdx.x;
  float p = 0.f;
  for (int n = tid; n < NRES; n += 256) p += We1[(size_t)h * NRES + n] * bias_big[2048 + n];
  for (int m = 1; m < 64; m <<= 1) p += __shfl_xor(p, m);
  __shared__ float r4[4];
  if ((tid & 63) == 0) r4[tid >> 6] = p;
  __syncthreads();
  if (tid == 0) bias_big[4096 + h] = r4[0] + r4[1] + r4[2] + r4[3] + be1[h];
}

__global__ void __launch_bounds__(256) k_gemm1(const float* __restrict__ Wproj,
                                               const float* __restrict__ Wv,
                                               _Float16* __restrict__ wbig) {
  __shared__ _Float16 BT[64][40];
  const int kblock = blockIdx.x, cblock = blockIdx.y;
  const int tid = threadIdx.x, wv = tid >> 6, lane = tid & 63;
  const int l4 = lane >> 4, l15 = lane & 15;
  const int crow0 = cblock * 64 + wv * 16;
  f32x4 acc[4];
  f32x4 zero = {0.f, 0.f, 0.f, 0.f};
  for (int i = 0; i < 4; ++i) acc[i] = zero;

  for (int mc = 0; mc < 64; ++mc) {
    const int m0 = mc * 32;
    {
      int m = tid >> 3, kk = (tid & 7) * 8;
      const float* src = &Wv[(size_t)(m0 + m) * NRES + kblock * 64 + kk];
      float4 v0 = *(const float4*)src;
      float4 v1 = *(const float4*)(src + 4);
      float tmp[8] = {v0.x, v0.y, v0.z, v0.w, v1.x, v1.y, v1.z, v1.w};
      #pragma unroll
      for (int j = 0; j < 8; ++j) BT[kk + j][m] = (_Float16)tmp[j];
    }
    __syncthreads();
    const float* pa = &Wproj[(size_t)(crow0 + l15) * NRES + m0 + l4 * 8];
    float4 a0 = *(const float4*)pa;
    float4 a1 = *(const float4*)(pa + 4);
    f16x8 af;
    af[0]=(_Float16)a0.x; af[1]=(_Float16)a0.y; af[2]=(_Float16)a0.z; af[3]=(_Float16)a0.w;
    af[4]=(_Float16)a1.x; af[5]=(_Float16)a1.y; af[6]=(_Float16)a1.z; af[7]=(_Float16)a1.w;
    #pragma unroll
    for (int kt = 0; kt < 4; ++kt) {
      f16x8 bf = *(const f16x8*)&BT[kt * 16 + l15][l4 * 8];
      acc[kt] = MFMA(af, bf, acc[kt]);
    }
    __syncthreads();
  }
  #pragma unroll
  for (int kt = 0; kt < 4; ++kt)
    #pragma unroll
    for (int i = 0; i < 4; ++i) {
      int c = crow0 + l4 * 4 + i;
      int k = kblock * 64 + kt * 16 + l15;
      wbig[(size_t)(2048 + c) * NRES + k] = (_Float16)acc[kt][i];
    }
}

// W_h1 = We1 @ W_att -> wh1[0:128]
__global__ void __launch_bounds__(256) k_gemm2(const float* __restrict__ We1,
                                               const _Float16* __restrict__ wbig,
                                               _Float16* __restrict__ wh1) {
  __shared__ _Float16 BT[64][40];
  const int kblock = blockIdx.x, hblock = blockIdx.y;
  const int tid = threadIdx.x, wv = tid >> 6, lane = tid & 63;
  const int l4 = lane >> 4, l15 = lane & 15;
  const int hrow0 = hblock * 64 + wv * 16;
  f32x4 acc[4];
  f32x4 zero = {0.f, 0.f, 0.f, 0.f};
  for (int i = 0; i < 4; ++i) acc[i] = zero;

  for (int nc = 0; nc < 64; ++nc) {
    const int n0 = nc * 32;
    {
      int n = tid >> 3, kk = (tid & 7) * 8;
      f16x8 v = *(const f16x8*)&wbig[(size_t)(2048 + n0 + n) * NRES + kblock * 64 + kk];
      #pragma unroll
      for (int j = 0; j < 8; ++j) BT[kk + j][n] = v[j];
    }
    __syncthreads();
    const float* pa = &We1[(size_t)(hrow0 + l15) * NRES + n0 + l4 * 8];
    float4 a0 = *(const float4*)pa;
    float4 a1 = *(const float4*)(pa + 4);
    f16x8 af;
    af[0]=(_Float16)a0.x; af[1]=(_Float16)a0.y; af[2]=(_Float16)a0.z; af[3]=(_Float16)a0.w;
    af[4]=(_Float16)a1.x; af[5]=(_Float16)a1.y; af[6]=(_Float16)a1.z; af[7]=(_Float16)a1.w;
    #pragma unroll
    for (int kt = 0; kt < 4; ++kt) {
      f16x8 bf = *(const f16x8*)&BT[kt * 16 + l15][l4 * 8];
      acc[kt] = MFMA(af, bf, acc[kt]);
    }
    __syncthreads();
  }
  #pragma unroll
  for (int kt = 0; kt < 4; ++kt)
    #pragma unroll
    for (int i = 0; i < 4; ++i) {
      int h = hrow0 + l4 * 4 + i;
      int k = kblock * 64 + kt * 16 + l15;
      wh1[(size_t)h * NRES + k] = (_Float16)acc[kt][i];
    }
}

// ---------------- slot/wake barrier (collector-based, contention-free) ----------------
__device__ __forceinline__ void gbar3(unsigned* slots, unsigned* wake, int b, unsigned phase) {
  asm volatile("s_waitcnt vmcnt(0)" ::: "memory");   // drain all sc1 stores (write-acked)
  __syncthreads();
  if (threadIdx.x == 0) {
    __hip_atomic_store(slots + b, phase, __ATOMIC_RELAXED, __HIP_MEMORY_SCOPE_AGENT);
    unsigned spins = 0;
    while (__hip_atomic_load(wake + (size_t)b * 16, __ATOMIC_RELAXED, __HIP_MEMORY_SCOPE_AGENT) < phase) {
      __builtin_amdgcn_s_sleep(1);
      if (++spins > (1u << 20)) break;   // safety bail: wrong answer, not hang
    }
    (void)__hip_atomic_load(wake + (size_t)b * 16, __ATOMIC_ACQUIRE, __HIP_MEMORY_SCOPE_AGENT);
  }
  __syncthreads();
}

// ---------------- main persistent kernel ----------------

__global__ void __launch_bounds__(256, 2) k_main(
    const float* __restrict__ x,
    const float* __restrict__ ln_g, const float* __restrict__ ln_b,
    const float* __restrict__ be2v, const float* __restrict__ be3v,
    const float* __restrict__ w_mu, const float* __restrict__ w_rho,
    const float* __restrict__ b_mu, const float* __restrict__ b_rho,
    const float* __restrict__ w_eps, const float* __restrict__ b_eps,
    const _Float16* __restrict__ wbig, const _Float16* __restrict__ wh1,
    const float* __restrict__ bias_big,
    const _Float16* __restrict__ we2h, const _Float16* __restrict__ we3h,
    const _Float16* __restrict__ winh,
    _Float16* s16, float* yp,
    unsigned* cnt, float* __restrict__ out)
{
  const int b = blockIdx.x, tid = threadIdx.x;
  unsigned* slots = cnt;          // 256 u32 (padded region to 512)
  unsigned* wake  = cnt + 512;    // 256 lines, stride 16 u32 (64 B)

  // ===== collector block =====
  if (b == NWORK) {
    if (tid >= 64) return;
    for (unsigned p = 1; p <= 2u * TSTEPS; ++p) {
      unsigned spins = 0;
      for (;;) {
        bool ok = true;
        #pragma unroll
        for (int j = 0; j < 4; ++j) {
          unsigned v = __hip_atomic_load(slots + tid + j * 64, __ATOMIC_RELAXED, __HIP_MEMORY_SCOPE_AGENT);
          ok = ok && (v >= p);
        }
        if (__all((int)ok)) break;
        if (++spins > (1u << 19)) break;
        __builtin_amdgcn_s_sleep(1);
      }
      #pragma unroll
      for (int j = 0; j < 4; ++j)
        __hip_atomic_store(wake + (size_t)(tid + j * 64) * 16, p, __ATOMIC_RELAXED, __HIP_MEMORY_SCOPE_AGENT);
    }
    return;
  }

  const int wv = tid >> 6, lane = tid & 63;
  const int l4 = lane >> 4, l15 = lane & 15;

  // LDS total 63,488 B  ->  2 blocks/CU fit (127 KB of 160 KB), collector co-resident
  __shared__ float    lds_red[4][64][17];    // S1 K-split reduce (17.4 KB)
  __shared__ _Float16 lds_w2[128][136];      // We2 resident (34.8 KB)
  __shared__ _Float16 lds_h1[16][136];       // gelu(LN(h1))
  __shared__ _Float16 lds_g2[16][136];       // gelu(h2)
  __shared__ _Float16 lds_x[16][40];         // x_t rows (f16)
  __shared__ _Float16 lds_ns[16][40];        // new-state bounce for coalesced store

  // ---- S1: strip b (16 cols, full K, 4-wave K-split); blocks 0..7 also one h1 strip
  const bool dual = (b < 8);
  f16x8 Bf[16];
  #pragma unroll
  for (int ks = 0; ks < 16; ++ks)
    Bf[ks] = *(const f16x8*)&wbig[(size_t)(b * 16 + l15) * NRES + wv * 512 + ks * 32 + l4 * 8];
  const _Float16* wh1p = &wh1[(size_t)(b * 16 + l15) * NRES + wv * 512 + l4 * 8];

  // ---- S3 identity: all workers own 16 rows x 32 cols ----
  const int R0 = (b >> 6) * 16, C0 = (b & 63) * 32;

  float g8[8], bb8[8], bh8[8];
  #pragma unroll
  for (int jj = 0; jj < 8; ++jj) {
    g8[jj]  = ln_g[l15 + 16 * jj];
    bb8[jj] = ln_b[l15 + 16 * jj];
    bh8[jj] = bias_big[4096 + l15 + 16 * jj];
  }
  float be2r[2];
  #pragma unroll
  for (int ct = 0; ct < 2; ++ct) be2r[ct] = be2v[(wv * 2 + ct) * 16 + l15];

  const int mycol = C0 + wv * 16 + l15;   // waves 0,1 update these cols
  f16x8 We3f[4];
  f16x8 Winf;
  float be3r = 0.f, battr = 0.f;
  if (wv < 2) {
    #pragma unroll
    for (int ks = 0; ks < 4; ++ks)
      We3f[ks] = *(const f16x8*)&we3h[(size_t)mycol * HDIM + ks * 32 + l4 * 8];
    be3r  = be3v[mycol];
    battr = bias_big[2048 + mycol];
    Winf  = *(const f16x8*)&winh[(size_t)mycol * DIN + l4 * 8];
  }

  { // stage We2 into LDS once
    int row = tid >> 1, half = tid & 1;
    #pragma unroll
    for (int j = 0; j < 8; ++j) {
      f16x8 v = *(const f16x8*)&we2h[(size_t)row * HDIM + half * 64 + j * 8];
      *(f16x8*)&lds_w2[row][half * 64 + j * 8] = v;
    }
  }
  __syncthreads();

  const f32x4 zero = {0.f, 0.f, 0.f, 0.f};
  unsigned phase = 0;

  // consumer mapping for coalesced yp store: row cr = tid>>2, 4-col chunk cch = tid&3
  const int cr  = tid >> 2, cch = tid & 3;
  const int rqi = (cr >> 4) * 4 + (cr & 3);       // acc element index q*4+i
  const int pl4 = (cr >> 2) & 3;                  // producer l4

  for (int t = 0; t < TSTEPS; ++t) {
    // ===== S1: Y[:, strips] = s @ W.T (4-wave K-split) =====
    f32x4 a0 = zero, a1 = zero, a2 = zero, a3 = zero;
    f32x4 e0 = zero, e1 = zero, e2 = zero, e3 = zero;
    #pragma unroll
    for (int ks = 0; ks < 16; ++ks) {
      const int kk = wv * 512 + ks * 32 + l4 * 8;
      f16x8 A0 = *(const f16x8*)&s16[(size_t)(l15) * NRES + kk];
      f16x8 A1 = *(const f16x8*)&s16[(size_t)(16 + l15) * NRES + kk];
      f16x8 A2 = *(const f16x8*)&s16[(size_t)(32 + l15) * NRES + kk];
      f16x8 A3 = *(const f16x8*)&s16[(size_t)(48 + l15) * NRES + kk];
      a0 = MFMA(A0, Bf[ks], a0);
      a1 = MFMA(A1, Bf[ks], a1);
      a2 = MFMA(A2, Bf[ks], a2);
      a3 = MFMA(A3, Bf[ks], a3);
      if (dual) {   // streamed B fragment (L2/MALL, overlapped with MFMAs)
        f16x8 Bx = *(const f16x8*)&wh1p[ks * 32];
        e0 = MFMA(A0, Bx, e0);
        e1 = MFMA(A1, Bx, e1);
        e2 = MFMA(A2, Bx, e2);
        e3 = MFMA(A3, Bx, e3);
      }
    }
    #pragma unroll
    for (int i = 0; i < 4; ++i) {
      lds_red[wv][lane][0 + i]  = a0[i];
      lds_red[wv][lane][4 + i]  = a1[i];
      lds_red[wv][lane][8 + i]  = a2[i];
      lds_red[wv][lane][12 + i] = a3[i];
    }
    __syncthreads();
    { // coalesced reduce+store: thread -> (row cr, cols cch*4..cch*4+3)
      f32x4 v;
      #pragma unroll
      for (int c = 0; c < 4; ++c) {
        int pl = pl4 * 16 + cch * 4 + c;
        v[c] = lds_red[0][pl][rqi] + lds_red[1][pl][rqi]
             + lds_red[2][pl][rqi] + lds_red[3][pl][rqi];
      }
      stg16(&yp[(size_t)cr * WCOLS + b * 16 + cch * 4], v);
    }
    if (dual) {  // second pass through the same reduce buffer for the h1 strip
      __syncthreads();   // first-pass reads complete
      #pragma unroll
      for (int i = 0; i < 4; ++i) {
        lds_red[wv][lane][0 + i]  = e0[i];
        lds_red[wv][lane][4 + i]  = e1[i];
        lds_red[wv][lane][8 + i]  = e2[i];
        lds_red[wv][lane][12 + i] = e3[i];
      }
      __syncthreads();
      f32x4 v2;
      #pragma unroll
      for (int c = 0; c < 4; ++c) {
        int pl = pl4 * 16 + cch * 4 + c;
        v2[c] = lds_red[0][pl][rqi] + lds_red[1][pl][rqi]
              + lds_red[2][pl][rqi] + lds_red[3][pl][rqi];
      }
      stg16(&yp[(size_t)cr * WCOLS + 4096 + b * 16 + cch * 4], v2);
    }
    ++phase;
    gbar3(slots, wake, b, phase);

    // ===== S3: LN -> GELU -> We2 -> GELU -> We3 -> state update =====
    { // stage x_t (16 rows x 32) as f16
      int xr = tid >> 4, k0 = (tid & 15) * 2;
      const float* xs = &x[((size_t)(R0 + xr) * TSTEPS + t) * DIN + k0];
      lds_x[xr][k0]     = (_Float16)xs[0];
      lds_x[xr][k0 + 1] = (_Float16)xs[1];
    }
    // h1 + bias, LayerNorm over 128, exact GELU (row lr = wv*4+l4)
    const int lr = wv * 4 + l4;
    float h1v[8], s1 = 0.f, s2 = 0.f;
    const size_t yb = (size_t)(R0 + lr) * WCOLS + 4096;
    #pragma unroll
    for (int jj = 0; jj < 8; ++jj) {
      float v = yp[yb + l15 + 16 * jj] + bh8[jj];
      h1v[jj] = v; s1 += v; s2 += v * v;
    }
    #pragma unroll
    for (int m = 1; m < 16; m <<= 1) { s1 += __shfl_xor(s1, m); s2 += __shfl_xor(s2, m); }
    const float mu = s1 * (1.f / 128.f);
    const float var = s2 * (1.f / 128.f) - mu * mu;
    const float rs = rsqrtf(var + 1e-5f);
    #pragma unroll
    for (int jj = 0; jj < 8; ++jj) {
      float hn = (h1v[jj] - mu) * rs * g8[jj] + bb8[jj];
      lds_h1[lr][l15 + 16 * jj] = (_Float16)gelu_exact(hn);
    }
    __syncthreads();
    // h2 = gelu(h1g @ We2^T + be2): wave wv does col-tiles wv*2, wv*2+1
    f32x4 c0 = zero, c1 = zero;
    #pragma unroll
    for (int ks = 0; ks < 4; ++ks) {
      f16x8 af = *(const f16x8*)&lds_h1[l15][ks * 32 + l4 * 8];
      f16x8 b0 = *(const f16x8*)&lds_w2[(wv * 2 + 0) * 16 + l15][ks * 32 + l4 * 8];
      f16x8 b1 = *(const f16x8*)&lds_w2[(wv * 2 + 1) * 16 + l15][ks * 32 + l4 * 8];
      c0 = MFMA(af, b0, c0);
      c1 = MFMA(af, b1, c1);
    }
    #pragma unroll
    for (int i = 0; i < 4; ++i) {
      int rr = l4 * 4 + i;
      lds_g2[rr][(wv * 2 + 0) * 16 + l15] = (_Float16)gelu_exact(c0[i] + be2r[0]);
      lds_g2[rr][(wv * 2 + 1) * 16 + l15] = (_Float16)gelu_exact(c1[i] + be2r[1]);
    }
    __syncthreads();
    // phys + input-term + state update: waves 0,1 own cols C0..C0+31
    if (wv < 2) {
      f32x4 accp = zero;
      #pragma unroll
      for (int ks = 0; ks < 4; ++ks) {
        f16x8 af = *(const f16x8*)&lds_g2[l15][ks * 32 + l4 * 8];
        accp = MFMA(af, We3f[ks], accp);
      }
      f16x8 ax = *(const f16x8*)&lds_x[l15][l4 * 8];
      f32x4 acci = MFMA(ax, Winf, zero);
      #pragma unroll
      for (int i = 0; i < 4; ++i) {
        int r2 = l4 * 4 + i;
        float satt = yp[(size_t)(R0 + r2) * WCOLS + 2048 + mycol] + battr;
        float rrv  = yp[(size_t)(R0 + r2) * WCOLS + mycol];
        float ns = 0.7f * satt + 0.3f * tanhf(acci[i] + rrv + accp[i] + be3r);
        lds_ns[r2][wv * 16 + l15] = (_Float16)ns;
      }
    }
    __syncthreads();
    if (tid < 64) {  // coalesced s16 store: row r, 8-col chunk ch (16B each, 64B/row)
      int r = tid >> 2, ch = tid & 3;
      f16x8 v = *(const f16x8*)&lds_ns[r][ch * 8];
      stg16(&s16[(size_t)(R0 + r) * NRES + C0 + ch * 8], __builtin_bit_cast(f32x4, v));
    }
    ++phase;
    gbar3(slots, wake, b, phase);
  }

  // ---- Bayesian output head (blocks 0..63, after final barrier+acquire) ----
  if (b < BBATCH) {
    float* red = &lds_red[0][0][0];
    int o = tid >> 4, sg = tid & 15;
    float p = 0.f;
    for (int n = sg * 128; n < sg * 128 + 128; ++n) {
      float sv = (float)s16[(size_t)b * NRES + n];
      float w = w_mu[(size_t)o * NRES + n]
              + log1pf(expf(w_rho[(size_t)o * NRES + n])) * w_eps[(size_t)o * NRES + n];
      p += sv * w;
    }
    red[o * 17 + sg] = p;
    __syncthreads();
    if (tid < DOUT) {
      float sum = 0.f;
      for (int q = 0; q < 16; ++q) sum += red[tid * 17 + q];
      float bs = b_mu[tid] + log1pf(expf(b_rho[tid])) * b_eps[tid];
      out[b * DOUT + tid] = sum + bs;
    }
  }
}

// ---------------- host ----------------

extern "C" void kernel_launch(void* const* d_in, const int* in_sizes, int n_in,
                              void* d_out, int out_size, void* d_ws, size_t ws_size,
                              hipStream_t stream) {
  (void)in_sizes; (void)n_in; (void)out_size; (void)ws_size;
  const float* x     = (const float*)d_in[0];
  const float* W_in  = (const float*)d_in[1];
  const float* W_res = (const float*)d_in[2];
  const float* Wv    = (const float*)d_in[3];
  const float* bv    = (const float*)d_in[4];
  const float* Wproj = (const float*)d_in[5];
  const float* bproj = (const float*)d_in[6];
  const float* We1   = (const float*)d_in[7];
  const float* be1   = (const float*)d_in[8];
  const float* ln_g  = (const float*)d_in[9];
  const float* ln_b  = (const float*)d_in[10];
  const float* We2   = (const float*)d_in[11];
  const float* be2   = (const float*)d_in[12];
  const float* We3   = (const float*)d_in[13];
  const float* be3   = (const float*)d_in[14];
  const float* w_mu  = (const float*)d_in[15];
  const float* w_rho = (const float*)d_in[16];
  const float* b_mu  = (const float*)d_in[17];
  const float* b_rho = (const float*)d_in[18];
  const float* w_eps = (const float*)d_in[19];
  const float* b_eps = (const float*)d_in[20];
  float* out = (float*)d_out;

  char* ws = (char*)d_ws;
  _Float16* wbig     = (_Float16*)(ws + OFF_WBIG);
  _Float16* wh1      = (_Float16*)(ws + OFF_WH1);
  float*    bias_big = (float*)(ws + OFF_BIAS);
  _Float16* we2h     = (_Float16*)(ws + OFF_WE2H);
  _Float16* we3h     = (_Float16*)(ws + OFF_WE3H);
  _Float16* s16      = (_Float16*)(ws + OFF_S16);
  float*    yp       = (float*)(ws + OFF_YP);
  _Float16* winh     = (_Float16*)(ws + OFF_WINH);
  unsigned* cnt      = (unsigned*)(ws + OFF_CNT);

  hipMemsetAsync(bias_big, 0, WCOLS * sizeof(float), stream);
  hipMemsetAsync(s16, 0, (size_t)BBATCH * NRES * sizeof(_Float16), stream);
  hipMemsetAsync(cnt, 0, 512 * 4 + 256 * 64, stream);   // slots + wake lines

  k_cast<<<4096, 256, 0, stream>>>(W_res, wbig, NRES * NRES);                  // wbig[0:2048]
  k_cast<<<64,   256, 0, stream>>>(We2, we2h, HDIM * HDIM);
  k_cast<<<1024, 256, 0, stream>>>(We3, we3h, NRES * HDIM);
  k_cast<<<256,  256, 0, stream>>>(W_in, winh, NRES * DIN);
  k_batt<<<NRES, 256, 0, stream>>>(Wproj, bv, bproj, bias_big);
  k_gemm1<<<dim3(32, 32), 256, 0, stream>>>(Wproj, Wv, wbig);                  // wbig[2048:4096]
  k_bh1<<<HDIM, 256, 0, stream>>>(We1, be1, bias_big);
  k_gemm2<<<dim3(32, 2), 256, 0, stream>>>(We1, wbig, wh1);                    // wh1[0:128]

  k_main<<<NBLK, 256, 0, stream>>>(x, ln_g, ln_b, be2, be3,
                                   w_mu, w_rho, b_mu, b_rho, w_eps, b_eps,
                                   wbig, wh1, bias_big, we2h, we3h, winh, s16, yp, cnt, out);
}